// Round 2
// baseline (7410.427 us; speedup 1.0000x reference)
//
#include <hip/hip_runtime.h>
#include <math.h>

// TokenChoiceTopKRouter, round 2: expert-split waves, transposed-f4 LDS tiles.
//
// 256 blocks x 512 threads (8 waves). Block = 64 tokens; wave w owns experts
// 8w..8w+7 over the FULL K=4096. Lane (mt=lane>>3, nt=lane&7) accumulates
// 8 tokens {8i+mt} x 1 expert (8w+nt) -> float acc[8], no cross-wave reduce,
// no spill. Per 64-wide K chunk both x and w are staged in LDS transposed at
// float4 granularity: tile[slot p][row r], stride 64 f4. All inner-loop reads
// are affine (immediate offsets) and bank-conflict-free; staging writes eat a
// 16-way conflict on 4 instrs/thread/chunk (negligible).

constexpr int DIM    = 4096;
constexpr int NE     = 64;
constexpr int BM     = 64;            // tokens per block
constexpr int BK     = 64;            // k per chunk
constexpr int NCHUNK = DIM / BK;      // 64
constexpr int TBUF   = 1024;          // f4 per tile buffer (16 slots x 64 rows)
constexpr int WBASE  = 2 * TBUF;      // f4 offset of w tiles (x dbuf first)

__global__ __launch_bounds__(512, 2)
void router_kernel(const float* __restrict__ x, const float* __restrict__ w,
                   const float* __restrict__ bias,
                   float* __restrict__ out_scores, float* __restrict__ out_idx,
                   float* __restrict__ counts) {
  __shared__ float4 lds4[4 * TBUF];   // 65536 B: x dbuf (2x1024 f4) + w dbuf
  float* ldsf = (float*)lds4;

  const int tid  = threadIdx.x;
  const int wave = tid >> 6;
  const int lane = tid & 63;
  const int mt   = lane >> 3;         // token sub-index: tokens {8i + mt}
  const int nt   = lane & 7;          // expert sub-index
  const int er   = wave * 8 + nt;     // this lane's expert
  const int tok0 = blockIdx.x * BM;

  // staging map: q = it*512 + tid -> row r = q>>4 (token or expert),
  // k-slot p = q&15. Global read: 16 consecutive lanes = 256 B of one row
  // (coalesced). LDS write: tile[p*64 + r] (f4-transposed).
  const int r0 = tid >> 4;            // q = tid      -> r
  const int r1 = (512 + tid) >> 4;    // q = 512+tid  -> r
  const int p0 = tid & 15;
  const int p1 = (512 + tid) & 15;    // == p0

  float acc[8];
#pragma unroll
  for (int i = 0; i < 8; ++i) acc[i] = 0.f;

  // ---- prologue: stage chunk 0 ----
  {
    float4 ax0 = *(const float4*)&x[(tok0 + r0) * DIM + p0 * 4];
    float4 ax1 = *(const float4*)&x[(tok0 + r1) * DIM + p1 * 4];
    float4 aw0 = *(const float4*)&w[r0 * DIM + p0 * 4];
    float4 aw1 = *(const float4*)&w[r1 * DIM + p1 * 4];
    lds4[p0 * 64 + r0]         = ax0;
    lds4[p1 * 64 + r1]         = ax1;
    lds4[WBASE + p0 * 64 + r0] = aw0;
    lds4[WBASE + p1 * 64 + r1] = aw1;
  }
  __syncthreads();

#pragma unroll 2
  for (int c = 0; c < NCHUNK; ++c) {
    // ---- issue next chunk's global loads early (latency hides under FMAs) --
    float4 nx0, nx1, nw0, nw1;
    if (c + 1 < NCHUNK) {
      const int k0 = (c + 1) * BK;
      nx0 = *(const float4*)&x[(tok0 + r0) * DIM + k0 + p0 * 4];
      nx1 = *(const float4*)&x[(tok0 + r1) * DIM + k0 + p1 * 4];
      nw0 = *(const float4*)&w[r0 * DIM + k0 + p0 * 4];
      nw1 = *(const float4*)&w[r1 * DIM + k0 + p1 * 4];
    }

    // ---- compute: 16 k-slots, 8 tokens, 1 expert per lane ----
    const float4* xt = lds4 + (c & 1) * TBUF + mt;          // + sp*64 + 8i
    const float4* wt = lds4 + WBASE + (c & 1) * TBUF + er;  // + sp*64
#pragma unroll
    for (int sp = 0; sp < 16; ++sp) {
      float4 b = wt[sp * 64];
#pragma unroll
      for (int i = 0; i < 8; ++i) {
        float4 a = xt[sp * 64 + i * 8];
        acc[i] = fmaf(a.x, b.x, acc[i]);
        acc[i] = fmaf(a.y, b.y, acc[i]);
        acc[i] = fmaf(a.z, b.z, acc[i]);
        acc[i] = fmaf(a.w, b.w, acc[i]);
      }
    }

    // ---- write next chunk into the other buffer, then barrier ----
    if (c + 1 < NCHUNK) {
      float4* xb = lds4 + ((c + 1) & 1) * TBUF;
      float4* wb = lds4 + WBASE + ((c + 1) & 1) * TBUF;
      xb[p0 * 64 + r0] = nx0;
      xb[p1 * 64 + r1] = nx1;
      wb[p0 * 64 + r0] = nw0;
      wb[p1 * 64 + r1] = nw1;
    }
    __syncthreads();
  }

  // ---- dump logits to LDS [64 tokens][64 experts], rotated cols ----
  float* logits = ldsf;  // reuse x-buf region (4096 floats)
#pragma unroll
  for (int i = 0; i < 8; ++i) {
    int t = i * 8 + mt;
    logits[t * 64 + ((er + t) & 63)] = acc[i];
  }
  __syncthreads();

  // ---- fused sigmoid + biased top-8 + normalize + histogram ----
  if ((lane & 7) == 0) {
    const int t  = wave * 8 + mt;
    const int gt = tok0 + t;
    float key[8], sv[8];
    int   idx[8];
#pragma unroll
    for (int j = 0; j < 8; ++j) { key[j] = -1e30f; sv[j] = 0.f; idx[j] = 0; }

    for (int e = 0; e < NE; ++e) {
      float l = logits[t * 64 + ((e + t) & 63)];
      float s = 1.0f / (1.0f + expf(-l));
      float k = s + bias[e];
      // bubble-insert; strict > keeps lower index on ties (lax.top_k order)
      float ck = k, cv = s; int ci = e;
#pragma unroll
      for (int j = 0; j < 8; ++j) {
        bool g = ck > key[j];
        float tk = key[j], tv = sv[j]; int ti = idx[j];
        key[j] = g ? ck : tk; sv[j] = g ? cv : tv; idx[j] = g ? ci : ti;
        ck = g ? tk : ck;     cv = g ? tv : cv;    ci = g ? ti : ci;
      }
    }

    float sum = 1e-20f;
#pragma unroll
    for (int j = 0; j < 8; ++j) sum += sv[j];
    float inv = 1.0f / sum;
#pragma unroll
    for (int j = 0; j < 8; ++j) {
      out_scores[gt * 8 + j] = sv[j] * inv;
      out_idx[gt * 8 + j]    = (float)idx[j];
      atomicAdd(&counts[idx[j]], 1.0f);
    }
  }
}

extern "C" void kernel_launch(void* const* d_in, const int* in_sizes, int n_in,
                              void* d_out, int out_size, void* d_ws, size_t ws_size,
                              hipStream_t stream) {
  const float* x    = (const float*)d_in[0];
  const float* w    = (const float*)d_in[1];
  const float* bias = (const float*)d_in[2];

  const int ntok = in_sizes[0] / DIM;        // 16384
  float* out        = (float*)d_out;
  float* out_scores = out;                   // [ntok*8]
  float* out_idx    = out + ntok * 8;        // [ntok*8] (indices as floats)
  float* counts     = out + 2 * ntok * 8;    // [64]

  hipMemsetAsync(counts, 0, NE * sizeof(float), stream);
  hipLaunchKernelGGL(router_kernel, dim3(ntok / BM), dim3(512), 0, stream,
                     x, w, bias, out_scores, out_idx, counts);
}

// Round 3
// 1052.118 us; speedup vs baseline: 7.0433x; 7.0433x over previous
//
#include <hip/hip_runtime.h>
#include <math.h>

// TokenChoiceTopKRouter, round 3: scalar-operand GEMM.
//
// Key idea: fp32 vector-GEMM streaming BOTH operands from LDS is LDS-issue
// bound (~12x over the FMA roofline). So w goes through SGPRs: wave
// (eh = expert-half, ks = K-slice) has wave-uniform w rows -> s_load ->
// v_fma_f32 with SGPR operand (1 scalar src allowed). x: lane = token,
// xr[16] VGPRs per chunk from a padded LDS tile (one read per element).
//
// 256 blocks x 512 threads (8 waves = 4 K-slices x 2 expert-halves).
// Lane L owns token L: acc[32] = 32 experts x 1 token. Epilogue: 2-phase
// rotated-column LDS reduction over the 4 K-slice partials, then fused
// sigmoid + biased top-8 + normalize + histogram (64 threads).

constexpr int DIM  = 4096;
constexpr int NE   = 64;
constexpr int BM   = 64;          // tokens per block
constexpr int KB   = 16;          // k per chunk per wave
constexpr int KSL  = 1024;        // K-slice per (ks) group
constexpr int NCH  = KSL / KB;    // 64 chunks
constexpr int XROW = 20;          // padded floats per (win,token) row
constexpr int BUFF4 = 4 * 64 * XROW / 4;  // 1280 f4 per staging buffer

__global__ __launch_bounds__(512, 2)
void router_kernel(const float* __restrict__ x, const float* __restrict__ w,
                   const float* __restrict__ bias,
                   float* __restrict__ out_scores, float* __restrict__ out_idx,
                   float* __restrict__ counts) {
  __shared__ float lds[10240];    // 40 KB. main: xs[2][4 win][64 tok][20]
                                  // epilogue: part[2][64 tok][64 exp] (32 KB)
  float4* lds4 = (float4*)lds;

  const int tid  = threadIdx.x;
  const int lane = tid & 63;                                   // == token-in-block
  const int wave = __builtin_amdgcn_readfirstlane(tid >> 6);
  const int eh   = wave & 1;                                   // expert half
  const int ks   = wave >> 1;                                  // K-slice 0..3
  const int tok0 = blockIdx.x * BM;

  // staging map: f4 id f in [0,1024): win=f>>8, t=(f>>2)&63, j=f&3
  const int f0 = tid, f1 = tid + 512;
  const int w0f = f0 >> 8, t0f = (f0 >> 2) & 63, j0f = f0 & 3;
  const int w1f = f1 >> 8, t1f = (f1 >> 2) & 63, j1f = f1 & 3;
  const float* gp0 = &x[(tok0 + t0f) * DIM + w0f * KSL + j0f * 4];
  const float* gp1 = &x[(tok0 + t1f) * DIM + w1f * KSL + j1f * 4];
  const int l0 = (w0f * 64 + t0f) * (XROW / 4) + j0f;          // f4 units
  const int l1 = (w1f * 64 + t1f) * (XROW / 4) + j1f;

  float acc[32];
#pragma unroll
  for (int i = 0; i < 32; ++i) acc[i] = 0.f;

  // ---- prologue: stage chunk 0 into buffer 0 ----
  {
    float4 g0 = *(const float4*)gp0;
    float4 g1 = *(const float4*)gp1;
    lds4[l0] = g0;
    lds4[l1] = g1;
  }
  __syncthreads();

  const int xrbase = (ks * 64 + lane) * (XROW / 4);            // f4 units

#pragma unroll 1
  for (int c = 0; c < NCH; ++c) {
    const int cb = c & 1, nb = cb ^ 1;

    // ---- per-lane x fragment for this chunk (4x ds_read_b128) ----
    float4 q0 = lds4[cb * BUFF4 + xrbase + 0];
    float4 q1 = lds4[cb * BUFF4 + xrbase + 1];
    float4 q2 = lds4[cb * BUFF4 + xrbase + 2];
    float4 q3 = lds4[cb * BUFF4 + xrbase + 3];
    const float xr[16] = {q0.x, q0.y, q0.z, q0.w, q1.x, q1.y, q1.z, q1.w,
                          q2.x, q2.y, q2.z, q2.w, q3.x, q3.y, q3.z, q3.w};

    // ---- issue next chunk's global loads (hide under FMAs) ----
    float4 g0, g1;
    if (c + 1 < NCH) {
      g0 = *(const float4*)(gp0 + (c + 1) * KB);
      g1 = *(const float4*)(gp1 + (c + 1) * KB);
    }

    // ---- compute: 32 experts x 16 k, w via wave-uniform s_load ----
    const float* wbase = w + (eh * 32) * DIM + ks * KSL + c * KB;
#pragma unroll
    for (int eg = 0; eg < 8; ++eg) {
      const float* wr0 = wbase + (eg * 4 + 0) * DIM;
      const float* wr1 = wbase + (eg * 4 + 1) * DIM;
      const float* wr2 = wbase + (eg * 4 + 2) * DIM;
      const float* wr3 = wbase + (eg * 4 + 3) * DIM;
#pragma unroll
      for (int k = 0; k < KB; ++k) {
        acc[eg * 4 + 0] = fmaf(xr[k], wr0[k], acc[eg * 4 + 0]);
        acc[eg * 4 + 1] = fmaf(xr[k], wr1[k], acc[eg * 4 + 1]);
        acc[eg * 4 + 2] = fmaf(xr[k], wr2[k], acc[eg * 4 + 2]);
        acc[eg * 4 + 3] = fmaf(xr[k], wr3[k], acc[eg * 4 + 3]);
      }
    }

    // ---- write next chunk to the other buffer, barrier ----
    if (c + 1 < NCH) {
      lds4[nb * BUFF4 + l0] = g0;
      lds4[nb * BUFF4 + l1] = g1;
    }
    __syncthreads();
  }

  // ---- 2-phase cross-K-slice reduction into part[2][64][64] (rotated cols) --
  if (ks < 2) {
#pragma unroll
    for (int j = 0; j < 32; ++j) {
      int e = eh * 32 + j;
      lds[ks * 4096 + lane * 64 + ((e + lane) & 63)] = acc[j];
    }
  }
  __syncthreads();
  if (ks >= 2) {
#pragma unroll
    for (int j = 0; j < 32; ++j) {
      int e = eh * 32 + j;
      lds[(ks - 2) * 4096 + lane * 64 + ((e + lane) & 63)] += acc[j];
    }
  }
  __syncthreads();

  // ---- fused sigmoid + biased top-8 + normalize + histogram ----
  if (tid < 64) {
    const int t  = tid;
    const int gt = tok0 + t;
    float key[8], sv[8];
    int   idx[8];
#pragma unroll
    for (int j = 0; j < 8; ++j) { key[j] = -1e30f; sv[j] = 0.f; idx[j] = 0; }

    for (int e = 0; e < NE; ++e) {
      int col = (e + t) & 63;
      float l = lds[t * 64 + col] + lds[4096 + t * 64 + col];
      float s = 1.0f / (1.0f + expf(-l));
      float k = s + bias[e];
      // bubble-insert; strict > keeps lower index on ties (lax.top_k order)
      float ck = k, cv = s; int ci = e;
#pragma unroll
      for (int j = 0; j < 8; ++j) {
        bool g = ck > key[j];
        float tk = key[j], tv = sv[j]; int ti = idx[j];
        key[j] = g ? ck : tk; sv[j] = g ? cv : tv; idx[j] = g ? ci : ti;
        ck = g ? tk : ck;     cv = g ? tv : cv;    ci = g ? ti : ci;
      }
    }

    float sum = 1e-20f;
#pragma unroll
    for (int j = 0; j < 8; ++j) sum += sv[j];
    float inv = 1.0f / sum;
#pragma unroll
    for (int j = 0; j < 8; ++j) {
      out_scores[gt * 8 + j] = sv[j] * inv;
      out_idx[gt * 8 + j]    = (float)idx[j];
      atomicAdd(&counts[idx[j]], 1.0f);
    }
  }
}

extern "C" void kernel_launch(void* const* d_in, const int* in_sizes, int n_in,
                              void* d_out, int out_size, void* d_ws, size_t ws_size,
                              hipStream_t stream) {
  const float* x    = (const float*)d_in[0];
  const float* w    = (const float*)d_in[1];
  const float* bias = (const float*)d_in[2];

  const int ntok = in_sizes[0] / DIM;        // 16384
  float* out        = (float*)d_out;
  float* out_scores = out;                   // [ntok*8]
  float* out_idx    = out + ntok * 8;        // [ntok*8] (indices as floats)
  float* counts     = out + 2 * ntok * 8;    // [64]

  hipMemsetAsync(counts, 0, NE * sizeof(float), stream);
  hipLaunchKernelGGL(router_kernel, dim3(ntok / BM), dim3(512), 0, stream,
                     x, w, bias, out_scores, out_idx, counts);
}